// Round 1
// 134.613 us; speedup vs baseline: 1.0858x; 1.0858x over previous
//
#include <hip/hip_runtime.h>
#include <cfloat>

// Problem constants: M=N=64 grid, DIM=512, B=4096, SIGMA=32
#define DIMK 512
#define MN   4096
#define BATCH 4096
#define NGRP 1024   // 4-column groups per row

typedef _Float16 half8_t __attribute__((ext_vector_type(8)));
typedef _Float16 half4_t __attribute__((ext_vector_type(4)));
typedef float f32x4 __attribute__((ext_vector_type(4)));

// async global->LDS, 16B per lane; LDS dest is wave-uniform base + lane*16
#define GLD16(gp, lp) __builtin_amdgcn_global_load_lds( \
    (const __attribute__((address_space(1))) void*)(gp), \
    (__attribute__((address_space(3))) void*)(lp), 16, 0, 0)

// ---------------------------------------------------------------------------
// Convert: X,W fp32 -> f16 RTN + exact fp32 row norms. (unchanged)
// ---------------------------------------------------------------------------
__global__ __launch_bounds__(256) void convert_kernel(
        const float* __restrict__ X, const float* __restrict__ W,
        _Float16* __restrict__ Xh, _Float16* __restrict__ Wh,
        float* __restrict__ w2, float* __restrict__ xnorm) {
    const int blk  = blockIdx.x;
    const int t    = threadIdx.x;
    const bool isW = blk >= 1024;
    const float* src = isW ? W : X;
    _Float16* dst  = isW ? Wh : Xh;
    const int rblk = isW ? blk - 1024 : blk;
    const size_t idx = (size_t)rblk * 2048 + (size_t)t * 8;

    float4 v0 = *(const float4*)(src + idx);
    float4 v1 = *(const float4*)(src + idx + 4);
    float v[8] = {v0.x, v0.y, v0.z, v0.w, v1.x, v1.y, v1.z, v1.w};
    half8_t hv;
    float s = 0.f;
#pragma unroll
    for (int e = 0; e < 8; e++) {
        s += v[e] * v[e];
        hv[e] = (_Float16)v[e];
    }
    *(half8_t*)(dst + idx) = hv;
#pragma unroll
    for (int o = 32; o > 0; o >>= 1) s += __shfl_down(s, o);
    if ((t & 63) == 0) {
        int row = rblk * 4 + (t >> 6);
        if (isW) w2[row] = s;
        else     xnorm[row] = __fsqrt_rn(s);
    }
}

// ---------------------------------------------------------------------------
// Score GEMM v2: 256x256 tile, 8 waves (2m x 4n), BK=64, 128KiB dbuf LDS,
// fragment-order staging (pre-permuted global source -> linear LDS dest ->
// conflict-free 1KB/wave ds_read_b128). 4 phases / K-tile, counted vmcnt(2)
// gate (never drains to 0 in main loop), raw s_barrier + lgkmcnt(0) +
// sched_barrier(0) + setprio around each 16-MFMA cluster (T3+T4+T5).
// XCD-bijective block swizzle: 8 XCDs x 32 blocks, each a 4x8 panel rect (T1).
// Group-min f16 epilogue identical math/layout to previous version.
// ---------------------------------------------------------------------------
#define MFMA_HALF(R) \
    do { \
        acc[(R)+0][0] = __builtin_amdgcn_mfma_f32_16x16x32_f16(ah0, bh0, acc[(R)+0][0], 0, 0, 0); \
        acc[(R)+0][1] = __builtin_amdgcn_mfma_f32_16x16x32_f16(ah0, bh1, acc[(R)+0][1], 0, 0, 0); \
        acc[(R)+0][2] = __builtin_amdgcn_mfma_f32_16x16x32_f16(ah0, bh2, acc[(R)+0][2], 0, 0, 0); \
        acc[(R)+0][3] = __builtin_amdgcn_mfma_f32_16x16x32_f16(ah0, bh3, acc[(R)+0][3], 0, 0, 0); \
        acc[(R)+1][0] = __builtin_amdgcn_mfma_f32_16x16x32_f16(ah1, bh0, acc[(R)+1][0], 0, 0, 0); \
        acc[(R)+1][1] = __builtin_amdgcn_mfma_f32_16x16x32_f16(ah1, bh1, acc[(R)+1][1], 0, 0, 0); \
        acc[(R)+1][2] = __builtin_amdgcn_mfma_f32_16x16x32_f16(ah1, bh2, acc[(R)+1][2], 0, 0, 0); \
        acc[(R)+1][3] = __builtin_amdgcn_mfma_f32_16x16x32_f16(ah1, bh3, acc[(R)+1][3], 0, 0, 0); \
        acc[(R)+2][0] = __builtin_amdgcn_mfma_f32_16x16x32_f16(ah2, bh0, acc[(R)+2][0], 0, 0, 0); \
        acc[(R)+2][1] = __builtin_amdgcn_mfma_f32_16x16x32_f16(ah2, bh1, acc[(R)+2][1], 0, 0, 0); \
        acc[(R)+2][2] = __builtin_amdgcn_mfma_f32_16x16x32_f16(ah2, bh2, acc[(R)+2][2], 0, 0, 0); \
        acc[(R)+2][3] = __builtin_amdgcn_mfma_f32_16x16x32_f16(ah2, bh3, acc[(R)+2][3], 0, 0, 0); \
        acc[(R)+3][0] = __builtin_amdgcn_mfma_f32_16x16x32_f16(ah3, bh0, acc[(R)+3][0], 0, 0, 0); \
        acc[(R)+3][1] = __builtin_amdgcn_mfma_f32_16x16x32_f16(ah3, bh1, acc[(R)+3][1], 0, 0, 0); \
        acc[(R)+3][2] = __builtin_amdgcn_mfma_f32_16x16x32_f16(ah3, bh2, acc[(R)+3][2], 0, 0, 0); \
        acc[(R)+3][3] = __builtin_amdgcn_mfma_f32_16x16x32_f16(ah3, bh3, acc[(R)+3][3], 0, 0, 0); \
    } while (0)

#define PHASE_TAIL(R) \
    do { \
        __builtin_amdgcn_s_barrier(); \
        asm volatile("s_waitcnt lgkmcnt(0)" ::: "memory"); \
        __builtin_amdgcn_sched_barrier(0); \
        __builtin_amdgcn_s_setprio(1); \
        MFMA_HALF(R); \
        __builtin_amdgcn_s_setprio(0); \
        __builtin_amdgcn_s_barrier(); \
    } while (0)

__global__ __launch_bounds__(512, 2) void score_kernel(
        const _Float16* __restrict__ Xh, const _Float16* __restrict__ Wh,
        const float* __restrict__ w2, float* __restrict__ Gm /* = d_out */) {
    // [buf][A/B][256 rows x 64 k, fragment-order] = 128 KiB
    __shared__ __align__(16) _Float16 lds[2][2][16384];

    const int t    = threadIdx.x;
    const int lane = t & 63;
    const int w    = t >> 6;        // wave 0..7
    const int wm   = w >> 2;        // m-half (0..1) -> 128 rows
    const int wn   = w & 3;         // n-quarter (0..3) -> 64 cols

    // XCD-bijective swizzle: id%8 -> XCD; each XCD owns a 4(m) x 8(n) rect
    const int id  = blockIdx.y * 16 + blockIdx.x;
    const int xcd = id & 7;
    const int li  = id >> 3;                 // 0..31
    const int bm  = (xcd >> 1) * 4 + (li >> 3);
    const int bn  = (xcd & 1) * 8 + (li & 7);
    const int m0  = bm * 256;
    const int n0  = bn * 256;

    // staging: thread t -> dest f16 (c*4096 + t*8) in frag-order layout
    // [rg(16)][ks(2)][sl(64)*8]; source row/k chosen so reads are linear.
    const int srow = ((t >> 7) << 4) + (t & 15);          // + c*64
    const int skof = ((t >> 6) & 1) * 32 + ((t >> 4) & 3) * 8;
    const _Float16* gA = Xh + (size_t)(m0 + srow) * DIMK + skof;
    const _Float16* gB = Wh + (size_t)(n0 + srow) * DIMK + skof;
    const int ldst = t * 8;

#define STG_A(b, kt, c) GLD16(gA + (size_t)(c) * (64 * DIMK) + (kt) * 64, &lds[b][0][(c) * 4096 + ldst])
#define STG_B(b, kt, c) GLD16(gB + (size_t)(c) * (64 * DIMK) + (kt) * 64, &lds[b][1][(c) * 4096 + ldst])
#define LDA(b, rg, ks) (*(const half8_t*)(&lds[b][0][(rg) * 1024 + (ks) * 512 + lane * 8]))
#define LDB(b, rg, ks) (*(const half8_t*)(&lds[b][1][(rg) * 1024 + (ks) * 512 + lane * 8]))

    f32x4 acc[8][4];
#pragma unroll
    for (int i = 0; i < 8; i++)
#pragma unroll
        for (int j = 0; j < 4; j++) acc[i][j] = (f32x4){0.f, 0.f, 0.f, 0.f};

    // prologue: stage K-tile 0 into buf 0 (8 loads in flight)
    STG_A(0, 0, 0); STG_A(0, 0, 1); STG_A(0, 0, 2); STG_A(0, 0, 3);
    STG_B(0, 0, 0); STG_B(0, 0, 1); STG_B(0, 0, 2); STG_B(0, 0, 3);

    half8_t ah0, ah1, ah2, ah3, bh0, bh1, bh2, bh3;

    for (int kt = 0; kt < 8; ++kt) {
        const int  b  = kt & 1;
        const int  nb = b ^ 1;
        const bool dn = kt < 7;

        // ---- K-tile gate: issue 2 next-tile loads, counted vmcnt ----
        if (dn) {
            STG_A(nb, kt + 1, 0); STG_A(nb, kt + 1, 1);
            asm volatile("s_waitcnt vmcnt(2)" ::: "memory");   // kt's 8 landed
        } else {
            asm volatile("s_waitcnt vmcnt(0)" ::: "memory");
        }
        __builtin_amdgcn_sched_barrier(0);
        __builtin_amdgcn_s_barrier();        // all waves' kt loads landed;
                                             // prev-tile reads already fenced by p3 barrier

        // ---- phase 0: rows wm*128+[0,64), k-sub 0 ----
        ah0 = LDA(b, wm * 8 + 0, 0); ah1 = LDA(b, wm * 8 + 1, 0);
        ah2 = LDA(b, wm * 8 + 2, 0); ah3 = LDA(b, wm * 8 + 3, 0);
        bh0 = LDB(b, wn * 4 + 0, 0); bh1 = LDB(b, wn * 4 + 1, 0);
        bh2 = LDB(b, wn * 4 + 2, 0); bh3 = LDB(b, wn * 4 + 3, 0);
        if (dn) { STG_A(nb, kt + 1, 2); STG_A(nb, kt + 1, 3); }
        PHASE_TAIL(0);

        // ---- phase 1: rows wm*128+[64,128), k-sub 0 (bh reused) ----
        ah0 = LDA(b, wm * 8 + 4, 0); ah1 = LDA(b, wm * 8 + 5, 0);
        ah2 = LDA(b, wm * 8 + 6, 0); ah3 = LDA(b, wm * 8 + 7, 0);
        if (dn) { STG_B(nb, kt + 1, 0); STG_B(nb, kt + 1, 1); }
        PHASE_TAIL(4);

        // ---- phase 2: rows wm*128+[0,64), k-sub 1 ----
        ah0 = LDA(b, wm * 8 + 0, 1); ah1 = LDA(b, wm * 8 + 1, 1);
        ah2 = LDA(b, wm * 8 + 2, 1); ah3 = LDA(b, wm * 8 + 3, 1);
        bh0 = LDB(b, wn * 4 + 0, 1); bh1 = LDB(b, wn * 4 + 1, 1);
        bh2 = LDB(b, wn * 4 + 2, 1); bh3 = LDB(b, wn * 4 + 3, 1);
        if (dn) { STG_B(nb, kt + 1, 2); STG_B(nb, kt + 1, 3); }
        PHASE_TAIL(0);

        // ---- phase 3: rows wm*128+[64,128), k-sub 1 ----
        ah0 = LDA(b, wm * 8 + 4, 1); ah1 = LDA(b, wm * 8 + 5, 1);
        ah2 = LDA(b, wm * 8 + 6, 1); ah3 = LDA(b, wm * 8 + 7, 1);
        PHASE_TAIL(4);
        // p3's trailing barrier = end-gate: all reads of buf b complete
        // before next iteration stages into it.
    }

    // ---- 4-col group mins -> f16. D layout: col=lane&15, row=(lane>>4)*4+v ----
    const int q   = lane >> 4;
    const int cl  = lane & 15;
    const int gb  = (n0 >> 2) + wn * 16;
    float w2v[4];
#pragma unroll
    for (int j = 0; j < 4; j++) w2v[j] = w2[n0 + wn * 64 + j * 16 + cl];
#pragma unroll
    for (int ai = 0; ai < 8; ai++)
#pragma unroll
        for (int v = 0; v < 4; v++) {
            const int row = m0 + wm * 128 + ai * 16 + q * 4 + v;
            _Float16* grow = (_Float16*)Gm + (size_t)row * 8192 + gb;
#pragma unroll
            for (int j = 0; j < 4; j++) {
                float s = w2v[j] - 2.0f * acc[ai][j][v];
                s = fminf(s, __shfl_xor(s, 1));
                s = fminf(s, __shfl_xor(s, 2));
                if ((cl & 3) == 0) grow[j * 4 + (cl >> 2)] = (_Float16)s;
            }
        }
}

// ---------------------------------------------------------------------------
// Epilogue: per-row f16 group-min screen + barrier-free exact fp32 rescore +
// separable Gaussian row write. (unchanged)
// ---------------------------------------------------------------------------
__global__ __launch_bounds__(256) void epilogue_kernel(
        const float* __restrict__ w2, const float* __restrict__ xnorm,
        const float* __restrict__ X, const float* __restrict__ W,
        const int* __restrict__ decay_p, const int* __restrict__ it_p,
        float* out) {
    __shared__ float xs[512];
    __shared__ int   list[NGRP];
    __shared__ int   cnt;
    __shared__ float wmin[4];
    __shared__ float svv[4];
    __shared__ int   svi[4];
    __shared__ float tab[128];
    const int row  = blockIdx.x;
    const int t    = threadIdx.x;
    const int lane = t & 63;
    const int w    = t >> 6;

    {
        float2 xv = *(const float2*)(X + (size_t)row * DIMK + t * 2);
        xs[2 * t]     = xv.x;
        xs[2 * t + 1] = xv.y;
    }
    if (t == 0) cnt = 0;

    // f16 group-mins: 4 per thread (8B coalesced)
    half4_t gmh = *((const half4_t*)((const _Float16*)out + (size_t)row * 8192) + t);
    float gme[4] = {(float)gmh[0], (float)gmh[1], (float)gmh[2], (float)gmh[3]};
    float g = fminf(fminf(gme[0], gme[1]), fminf(gme[2], gme[3]));
#pragma unroll
    for (int mask = 1; mask <= 32; mask <<= 1)
        g = fminf(g, __shfl_xor(g, mask));
    if (lane == 0) wmin[w] = g;
    __syncthreads();
    const float gmin = fminf(fminf(wmin[0], wmin[1]), fminf(wmin[2], wmin[3]));
    const float tau  = gmin + 2.0f * (0.0222f * xnorm[row] + 0.25f);

    // collect qualifying groups (unordered; explicit col tie-break later)
#pragma unroll
    for (int e = 0; e < 4; e++)
        if (gme[e] <= tau) list[atomicAdd(&cnt, 1)] = t * 4 + e;
    __syncthreads();
    const int total = cnt;            // >= 1 always (gmin's group qualifies)

    // barrier-free exact rescore: wave w owns groups w, w+4, w+8, ...
    float mbv = FLT_MAX;
    int   mbi = 0x7FFFFFFF;
    for (int idx = w; idx < total; idx += 4) {
        const int gid = list[idx];
#pragma unroll
        for (int cj = 0; cj < 4; cj++) {
            const int col = gid * 4 + cj;
            const float* wr = W + (size_t)col * DIMK;
            float p = 0.f;
#pragma unroll
            for (int e = 0; e < 8; e++) p += xs[lane * 8 + e] * wr[lane * 8 + e];
#pragma unroll
            for (int mask = 1; mask <= 32; mask <<= 1) p += __shfl_xor(p, mask);
            float s = w2[col] - 2.0f * p;
            if (s < mbv || (s == mbv && col < mbi)) { mbv = s; mbi = col; }
        }
    }
    if (lane == 0) { svv[w] = mbv; svi[w] = mbi; }
    __syncthreads();
    // merge (uniform across all threads; no extra sync needed)
    float sbv = svv[0]; int sbi = svi[0];
#pragma unroll
    for (int k = 1; k < 4; k++) {
        float s = svv[k]; int c = svi[k];
        if (s < sbv || (s == sbv && c < sbi)) { sbv = s; sbi = c; }
    }

    // separable Gaussian tables + row write (overwrites group-mins)
    const float lr  = __expf(-(float)(*it_p) / (float)(*decay_p));
    const float so  = 32.0f * lr;          // SIGMA = 32
    const float inv = 1.0f / (so * so);
    const int rr = sbi >> 6, cc = sbi & 63;
    if (t < 64) {
        float d = (float)(t - rr);
        tab[t] = __expf(-d * d * inv);
    } else if (t < 128) {
        float d = (float)(t - 64 - cc);
        tab[t] = __expf(-d * d * inv);
    }
    __syncthreads();
    const float* er = tab;
    const float* ec = tab + 64;
    f32x4* orow = (f32x4*)(out + (size_t)row * 4096);
#pragma unroll
    for (int qq = 0; qq < 4; qq++) {
        int f  = qq * 256 + t;
        int i  = f >> 4;
        int j0 = (f & 15) * 4;
        float e = er[i];
        f32x4 o = {e * ec[j0], e * ec[j0 + 1], e * ec[j0 + 2], e * ec[j0 + 3]};
        __builtin_nontemporal_store(o, orow + f);
    }
}

// ---------------------------------------------------------------------------
extern "C" void kernel_launch(void* const* d_in, const int* in_sizes, int n_in,
                              void* d_out, int out_size, void* d_ws, size_t ws_size,
                              hipStream_t stream) {
    const float* X       = (const float*)d_in[0];   // [4096,512]
    const float* W       = (const float*)d_in[1];   // [4096,512]
    const int*   decay_p = (const int*)d_in[3];
    const int*   it_p    = (const int*)d_in[4];
    float* out = (float*)d_out;                     // doubles as group-min scratch

    // ws: Xh (4MB) | Wh (4MB) | w2 16KB | xnorm 16KB
    _Float16* Xh = (_Float16*)d_ws;
    _Float16* Wh = Xh + (size_t)BATCH * DIMK;
    float*    w2 = (float*)(Wh + (size_t)MN * DIMK);
    float*    xn = w2 + MN;

    convert_kernel<<<2048, 256, 0, stream>>>(X, W, Xh, Wh, w2, xn);
    score_kernel<<<dim3(16, 16), 512, 0, stream>>>(Xh, Wh, w2, out);
    epilogue_kernel<<<BATCH, 256, 0, stream>>>(w2, xn, X, W, decay_p, it_p, out);
}